// Round 1
// baseline (791.916 us; speedup 1.0000x reference)
//
#include <hip/hip_runtime.h>
#include <cstdint>
#include <cstddef>

// Problem constants
#define B_    64
#define N_    64
#define D_    2048
#define NB_   8
#define W_    57           // N - NB + 1
#define QKVLD 6144         // q|k|v concatenated row stride
#define SCALE_ 0.022097086912079612f  // 1/sqrt(2048)

// ---------- helpers ----------
__device__ __forceinline__ float bf2f(unsigned short u){
  union { unsigned int i; float f; } x; x.i = ((unsigned int)u) << 16; return x.f;
}
__device__ __forceinline__ unsigned short f2bf(float f){
  union { float f; unsigned int i; } x; x.f = f;
  unsigned int r = x.i + 0x7fffu + ((x.i >> 16) & 1u);
  return (unsigned short)(r >> 16);
}
__device__ __forceinline__ void unpack8(const uint4 p, float* f){
  union { unsigned int i; float v; } x;
  x.i = p.x << 16;         f[0] = x.v;
  x.i = p.x & 0xffff0000u; f[1] = x.v;
  x.i = p.y << 16;         f[2] = x.v;
  x.i = p.y & 0xffff0000u; f[3] = x.v;
  x.i = p.z << 16;         f[4] = x.v;
  x.i = p.z & 0xffff0000u; f[5] = x.v;
  x.i = p.w << 16;         f[6] = x.v;
  x.i = p.w & 0xffff0000u; f[7] = x.v;
}

// ---------- cast fp32 -> bf16 (vectorized x4) ----------
__global__ __launch_bounds__(256) void cast_kernel(const float* __restrict__ s,
                                                   unsigned short* __restrict__ d, int n4){
  int i = blockIdx.x * 256 + threadIdx.x;
  if (i >= n4) return;
  const float4 v = ((const float4*)s)[i];
  ushort4 o; o.x = f2bf(v.x); o.y = f2bf(v.y); o.z = f2bf(v.z); o.w = f2bf(v.w);
  ((ushort4*)d)[i] = o;
}

// ---------- concat 3 bias vectors of D_ each ----------
__global__ __launch_bounds__(256) void concat_bias(const float* __restrict__ a,
                                                   const float* __restrict__ b,
                                                   const float* __restrict__ c,
                                                   float* __restrict__ o){
  int i = blockIdx.x * 256 + threadIdx.x;
  if (i >= 3 * D_) return;
  o[i] = (i < D_) ? a[i] : (i < 2 * D_) ? b[i - D_] : c[i - 2 * D_];
}

// ---------- bf16 GEMM: C[M][N] = A[M][K] @ B[N][K]^T + bias[N]  (m97 recipe) ----------
typedef __attribute__((ext_vector_type(8))) short bfrag8;   // 8 bf16 = 4 VGPR
typedef __attribute__((ext_vector_type(4))) float facc4;    // 4 fp32 acc

__global__ __launch_bounds__(256, 2) void gemm_bt(
    const unsigned short* __restrict__ A,
    const unsigned short* __restrict__ Bw,
    const float* __restrict__ bias,
    unsigned short* __restrict__ C,
    int M, int N, int K)
{
  __shared__ __align__(16) unsigned short lA[128 * 32];
  __shared__ __align__(16) unsigned short lB[128 * 32];
  const int t = threadIdx.x;
  const int lane = t & 63, wid = t >> 6;
  const int wm = wid >> 1, wn = wid & 1;
  const size_t rowBase = (size_t)blockIdx.x * 128;
  const size_t colBase = (size_t)blockIdx.y * 128;
  const int sr = lane >> 2, sg = lane & 3;     // staging: 4 lanes/row, 16B each

  const unsigned short* gA0 = A  + (rowBase + (size_t)(wid * 16 + sr)) * K + sg * 8;
  const unsigned short* gB0 = Bw + (colBase + (size_t)(wid * 16 + sr)) * K + sg * 8;
  unsigned short* lA0 = &lA[(wid * 16) * 32];  // wave-uniform LDS base
  unsigned short* lB0 = &lB[(wid * 16) * 32];

  facc4 acc[4][4];
  #pragma unroll
  for (int i = 0; i < 4; i++)
    #pragma unroll
    for (int j = 0; j < 4; j++) acc[i][j] = 0;

  const int fm = lane & 15, quad = lane >> 4;
  const unsigned short* aAddr = &lA[(wm * 64 + fm) * 32 + quad * 8];
  const unsigned short* bAddr = &lB[(wn * 64 + fm) * 32 + quad * 8];

#define STAGE(k0) do { \
    __builtin_amdgcn_global_load_lds((const __attribute__((address_space(1))) void*)(gA0 + (k0)),                 (__attribute__((address_space(3))) void*)(lA0),            16, 0, 0); \
    __builtin_amdgcn_global_load_lds((const __attribute__((address_space(1))) void*)(gA0 + (size_t)64*K + (k0)),  (__attribute__((address_space(3))) void*)(lA0 + 64*32),    16, 0, 0); \
    __builtin_amdgcn_global_load_lds((const __attribute__((address_space(1))) void*)(gB0 + (k0)),                 (__attribute__((address_space(3))) void*)(lB0),            16, 0, 0); \
    __builtin_amdgcn_global_load_lds((const __attribute__((address_space(1))) void*)(gB0 + (size_t)64*K + (k0)),  (__attribute__((address_space(3))) void*)(lB0 + 64*32),    16, 0, 0); \
  } while (0)

  STAGE(0);
  __syncthreads();
  for (int kt = 0;;) {
    bfrag8 af[4], bf[4];
    #pragma unroll
    for (int i = 0; i < 4; i++) {
      af[i] = *(const bfrag8*)(aAddr + i * 16 * 32);
      bf[i] = *(const bfrag8*)(bAddr + i * 16 * 32);
    }
    #pragma unroll
    for (int i = 0; i < 4; i++)
      #pragma unroll
      for (int j = 0; j < 4; j++)
        acc[i][j] = __builtin_amdgcn_mfma_f32_16x16x32_bf16(af[i], bf[j], acc[i][j], 0, 0, 0);
    kt += 32;
    if (kt >= K) break;
    __syncthreads();
    STAGE(kt);
    __syncthreads();
  }
#undef STAGE

  // epilogue: D row = quad*4+rr, col = lane&15 (m89/m91-verified layout)
  #pragma unroll
  for (int i = 0; i < 4; i++) {
    const size_t r0 = rowBase + wm * 64 + i * 16 + quad * 4;
    #pragma unroll
    for (int j = 0; j < 4; j++) {
      const size_t cc = colBase + wn * 64 + j * 16 + fm;
      const float bv = bias[cc];
      #pragma unroll
      for (int rr = 0; rr < 4; rr++)
        C[(r0 + rr) * (size_t)N + cc] = f2bf(acc[i][j][rr] + bv);
    }
  }
}

// ---------- NSA: per-batch band scores + softmax column-sum coefficients ----------
// c[b][w][j] = sum_i softmax_j( S[w+i][w+j] )  with S = q k^T * scale
__global__ __launch_bounds__(512) void nsa_coeff(const unsigned short* __restrict__ qkv,
                                                 float* __restrict__ cbuf){
  __shared__ float qs[64][65];
  __shared__ float ksT[64][65];
  __shared__ float Ss[64][65];
  const int b = blockIdx.x, t = threadIdx.x;
  const int lane = t & 63, wv = t >> 6;
  const unsigned short* qb = qkv + (size_t)b * 64 * QKVLD;
  float acc[8];
  #pragma unroll
  for (int j = 0; j < 8; j++) acc[j] = 0.f;
  const int r = t >> 3, gp = t & 7;
  for (int d0 = 0; d0 < 2048; d0 += 64) {
    const uint4 pq = *(const uint4*)(qb + (size_t)r * QKVLD + d0 + gp * 8);
    const uint4 pk = *(const uint4*)(qb + (size_t)r * QKVLD + 2048 + d0 + gp * 8);
    float fq[8], fk[8];
    unpack8(pq, fq); unpack8(pk, fk);
    #pragma unroll
    for (int m = 0; m < 8; m++) qs[r][gp * 8 + m] = fq[m];
    #pragma unroll
    for (int m = 0; m < 8; m++) ksT[gp * 8 + m][r] = fk[m];
    __syncthreads();
    #pragma unroll 4
    for (int dd = 0; dd < 64; dd++) {
      const float qv = qs[lane][dd];
      const float* kr = &ksT[dd][wv * 8];
      #pragma unroll
      for (int j = 0; j < 8; j++) acc[j] += qv * kr[j];
    }
    __syncthreads();
  }
  #pragma unroll
  for (int j = 0; j < 8; j++) Ss[lane][wv * 8 + j] = acc[j] * SCALE_;
  __syncthreads();
  if (t < W_ * 8) {
    const int wi = t >> 3, jp = t & 7;
    float csum = 0.f;
    for (int ip = 0; ip < 8; ip++) {
      const float* row = &Ss[wi + ip][wi];
      float mx = row[0];
      #pragma unroll
      for (int q = 1; q < 8; q++) mx = fmaxf(mx, row[q]);
      float s = 0.f, ej = 0.f;
      #pragma unroll
      for (int q = 0; q < 8; q++) { float e = __expf(row[q] - mx); s += e; if (q == jp) ej = e; }
      csum += ej / s;
    }
    cbuf[((size_t)b * W_ + wi) * 8 + jp] = csum;
  }
}

// ---------- h = fc @ ds_w^T (per-batch) + ds_b + nsa combine ----------
__global__ __launch_bounds__(256) void h_kernel(
    const float* __restrict__ fc, const float* __restrict__ dsw,
    const float* __restrict__ dsb, const unsigned short* __restrict__ qkv,
    const float* __restrict__ cbuf, float* __restrict__ h)
{
  const int b = blockIdx.y;
  const int d = blockIdx.x * 256 + threadIdx.x;
  __shared__ __align__(16) float dswl[W_ * 64];
  __shared__ float dsbl[W_];
  __shared__ float cl[W_ * 8];
  for (int i = threadIdx.x; i < W_ * 64; i += 256) dswl[i] = dsw[i];
  for (int i = threadIdx.x; i < W_ * 8; i += 256) cl[i] = cbuf[(size_t)b * W_ * 8 + i];
  if (threadIdx.x < W_) dsbl[threadIdx.x] = dsb[threadIdx.x];
  __syncthreads();
  float f[64];
  #pragma unroll
  for (int n = 0; n < 64; n++) f[n] = fc[((size_t)b * 64 + n) * 2048 + d];
  const unsigned short* vcol = qkv + (size_t)b * 64 * QKVLD + 4096 + d;
  float* hcol = h + (size_t)b * W_ * 2048 + d;
  for (int w = 0; w < W_; w++) {
    float acc = dsbl[w];
    const float4* dw4 = (const float4*)&dswl[w * 64];
    #pragma unroll
    for (int n4 = 0; n4 < 16; n4++) {
      const float4 dv = dw4[n4];
      acc += f[4*n4+0]*dv.x + f[4*n4+1]*dv.y + f[4*n4+2]*dv.z + f[4*n4+3]*dv.w;
    }
    float an = 0.f;
    #pragma unroll
    for (int j = 0; j < 8; j++) an += cl[w * 8 + j] * bf2f(vcol[(size_t)(w + j) * QKVLD]);
    hcol[(size_t)w * 2048] = acc + an;
  }
}

// ---------- LayerNorm + cast to bf16 (pads rows [3648,3712) with zeros) ----------
__global__ __launch_bounds__(256) void ln_kernel(
    const float* __restrict__ h, const float* __restrict__ g,
    const float* __restrict__ be, unsigned short* __restrict__ hn)
{
  const int r = blockIdx.x, t = threadIdx.x;
  unsigned short* orow = hn + (size_t)r * 2048;
  if (r >= B_ * W_) {
    for (int i = t; i < 2048; i += 256) orow[i] = 0;
    return;
  }
  const float* row = h + (size_t)r * 2048;
  const float4 v0 = ((const float4*)row)[t];
  const float4 v1 = ((const float4*)row)[t + 256];
  float s  = v0.x + v0.y + v0.z + v0.w + v1.x + v1.y + v1.z + v1.w;
  float s2 = v0.x*v0.x + v0.y*v0.y + v0.z*v0.z + v0.w*v0.w
           + v1.x*v1.x + v1.y*v1.y + v1.z*v1.z + v1.w*v1.w;
  #pragma unroll
  for (int off = 32; off >= 1; off >>= 1) { s += __shfl_down(s, off); s2 += __shfl_down(s2, off); }
  __shared__ float rs[4], rs2[4];
  if ((t & 63) == 0) { rs[t >> 6] = s; rs2[t >> 6] = s2; }
  __syncthreads();
  const float st  = rs[0] + rs[1] + rs[2] + rs[3];
  const float s2t = rs2[0] + rs2[1] + rs2[2] + rs2[3];
  const float mu  = st * (1.f / 2048.f);
  const float var = s2t * (1.f / 2048.f) - mu * mu;
  const float rstd = rsqrtf(var + 1e-5f);
  const float4 g0 = ((const float4*)g)[t],  g1 = ((const float4*)g)[t + 256];
  const float4 b0 = ((const float4*)be)[t], b1 = ((const float4*)be)[t + 256];
  ushort4 o0, o1;
  o0.x = f2bf((v0.x - mu) * rstd * g0.x + b0.x);
  o0.y = f2bf((v0.y - mu) * rstd * g0.y + b0.y);
  o0.z = f2bf((v0.z - mu) * rstd * g0.z + b0.z);
  o0.w = f2bf((v0.w - mu) * rstd * g0.w + b0.w);
  o1.x = f2bf((v1.x - mu) * rstd * g1.x + b1.x);
  o1.y = f2bf((v1.y - mu) * rstd * g1.y + b1.y);
  o1.z = f2bf((v1.z - mu) * rstd * g1.z + b1.z);
  o1.w = f2bf((v1.w - mu) * rstd * g1.w + b1.w);
  ((ushort4*)orow)[t] = o0;
  ((ushort4*)orow)[t + 256] = o1;
}

// ---------- final attention: scores, softmax column-sums, output combine ----------
__global__ __launch_bounds__(512) void sa2_kernel(const unsigned short* __restrict__ qkv2,
                                                  float* __restrict__ out){
  __shared__ float qs[64][65];
  __shared__ float ksT[64][65];
  __shared__ float Ss[64][65];
  __shared__ float rowm[64], rowsum[64], c2[64];
  const int b = blockIdx.x, t = threadIdx.x;
  const int lane = t & 63, wv = t >> 6;
  const unsigned short* qb = qkv2 + (size_t)b * W_ * QKVLD;
  float acc[8];
  #pragma unroll
  for (int j = 0; j < 8; j++) acc[j] = 0.f;
  const int r = t >> 3, gp = t & 7;
  for (int d0 = 0; d0 < 2048; d0 += 64) {
    const uint4 pq = *(const uint4*)(qb + (size_t)r * QKVLD + d0 + gp * 8);
    const uint4 pk = *(const uint4*)(qb + (size_t)r * QKVLD + 2048 + d0 + gp * 8);
    float fq[8], fk[8];
    unpack8(pq, fq); unpack8(pk, fk);
    #pragma unroll
    for (int m = 0; m < 8; m++) qs[r][gp * 8 + m] = fq[m];
    #pragma unroll
    for (int m = 0; m < 8; m++) ksT[gp * 8 + m][r] = fk[m];
    __syncthreads();
    #pragma unroll 4
    for (int dd = 0; dd < 64; dd++) {
      const float qv = qs[lane][dd];
      const float* kr = &ksT[dd][wv * 8];
      #pragma unroll
      for (int j = 0; j < 8; j++) acc[j] += qv * kr[j];
    }
    __syncthreads();
  }
  #pragma unroll
  for (int j = 0; j < 8; j++) Ss[lane][wv * 8 + j] = acc[j] * SCALE_;
  __syncthreads();
  if (t < W_) {
    float mx = -1e30f;
    for (int j = 0; j < W_; j++) mx = fmaxf(mx, Ss[t][j]);
    float s = 0.f;
    for (int j = 0; j < W_; j++) s += __expf(Ss[t][j] - mx);
    rowm[t] = mx; rowsum[t] = 1.f / s;
  }
  __syncthreads();
  if (t < W_) {
    float cs = 0.f;
    for (int i = 0; i < W_; i++) cs += __expf(Ss[i][t] - rowm[i]) * rowsum[i];
    c2[t] = cs;
  }
  __syncthreads();
  #pragma unroll
  for (int dl = 0; dl < 4; dl++) {
    const int d = t + dl * 512;
    float a = 0.f;
    for (int j = 0; j < W_; j++) a += c2[j] * bf2f(qb[(size_t)j * QKVLD + 4096 + d]);
    out[(size_t)b * 2048 + d] = a;
  }
}

// ---------- launch ----------
extern "C" void kernel_launch(void* const* d_in, const int* in_sizes, int n_in,
                              void* d_out, int out_size, void* d_ws, size_t ws_size,
                              hipStream_t stream)
{
  const float* fc  = (const float*)d_in[0];
  const float* nwq = (const float*)d_in[1];
  const float* nbq = (const float*)d_in[2];
  const float* nwk = (const float*)d_in[3];
  const float* nbk = (const float*)d_in[4];
  const float* nwv = (const float*)d_in[5];
  const float* nbv = (const float*)d_in[6];
  const float* dsw = (const float*)d_in[7];
  const float* dsb = (const float*)d_in[8];
  const float* lng = (const float*)d_in[9];
  const float* lnb = (const float*)d_in[10];
  const float* swq = (const float*)d_in[11];
  const float* sbq = (const float*)d_in[12];
  const float* swk = (const float*)d_in[13];
  const float* sbk = (const float*)d_in[14];
  const float* swv = (const float*)d_in[15];
  const float* sbv = (const float*)d_in[16];

  char* ws = (char*)d_ws;
  unsigned short* fc16 = (unsigned short*)(ws + 0);          // 16,777,216 B
  unsigned short* wcat = (unsigned short*)(ws + 16777216);   // 25,165,824 B (reused for sa weights)
  float* bcat1         = (float*)(ws + 41943040);            // 24,576 B
  float* bcat2         = (float*)(ws + 41967616);            // 24,576 B
  unsigned short* qkv  = (unsigned short*)(ws + 41992192);   // 50,331,648 B (reused for q2k2v2)
  float* cbuf          = (float*)(ws + 92323840);            // 116,736 B
  float* hbuf          = (float*)(ws + 92440576);            // 29,884,416 B
  unsigned short* hn   = (unsigned short*)(ws + 122324992);  // 15,204,352 B  (total ~137.5 MB)

  // casts + bias concat (nsa)
  cast_kernel<<<8192, 256, 0, stream>>>(fc, fc16, 2097152);
  cast_kernel<<<4096, 256, 0, stream>>>(nwq, wcat,            1048576);
  cast_kernel<<<4096, 256, 0, stream>>>(nwk, wcat + 4194304,  1048576);
  cast_kernel<<<4096, 256, 0, stream>>>(nwv, wcat + 8388608,  1048576);
  concat_bias<<<24, 256, 0, stream>>>(nbq, nbk, nbv, bcat1);

  // qkv = fc16 @ [wq;wk;wv]^T + bias   (M=4096, N=6144, K=2048)
  gemm_bt<<<dim3(32, 48), 256, 0, stream>>>(fc16, wcat, bcat1, qkv, 4096, 6144, 2048);

  // NSA band attention coefficients
  nsa_coeff<<<64, 512, 0, stream>>>(qkv, cbuf);

  // h = ds-projection + nsa combine
  h_kernel<<<dim3(8, 64), 256, 0, stream>>>(fc, dsw, dsb, qkv, cbuf, hbuf);

  // LayerNorm -> hn (bf16, padded to 3712 rows)
  ln_kernel<<<3712, 256, 0, stream>>>(hbuf, lng, lnb, hn);

  // casts + bias concat (sa) — wcat/qkv regions are free now
  cast_kernel<<<4096, 256, 0, stream>>>(swq, wcat,            1048576);
  cast_kernel<<<4096, 256, 0, stream>>>(swk, wcat + 4194304,  1048576);
  cast_kernel<<<4096, 256, 0, stream>>>(swv, wcat + 8388608,  1048576);
  concat_bias<<<24, 256, 0, stream>>>(sbq, sbk, sbv, bcat2);

  // q2k2v2 = hn @ [wq;wk;wv]^T + bias  (M=3712 padded, N=6144, K=2048)
  gemm_bt<<<dim3(29, 48), 256, 0, stream>>>(hn, wcat, bcat2, qkv, 3712, 6144, 2048);

  // final attention -> out (B, D) fp32
  sa2_kernel<<<64, 512, 0, stream>>>(qkv, (float*)d_out);

  (void)in_sizes; (void)n_in; (void)out_size; (void)ws_size;
}

// Round 2
// 544.643 us; speedup vs baseline: 1.4540x; 1.4540x over previous
//
#include <hip/hip_runtime.h>
#include <cstdint>
#include <cstddef>

// Problem constants
#define B_    64
#define N_    64
#define D_    2048
#define NB_   8
#define W_    57           // N - NB + 1
#define QKVLD 6144         // q|k|v concatenated row stride
#define SCALE_ 0.022097086912079612f  // 1/sqrt(2048)

// ---------- helpers ----------
__device__ __forceinline__ float bf2f(unsigned short u){
  union { unsigned int i; float f; } x; x.i = ((unsigned int)u) << 16; return x.f;
}
__device__ __forceinline__ unsigned short f2bf(float f){
  union { float f; unsigned int i; } x; x.f = f;
  unsigned int r = x.i + 0x7fffu + ((x.i >> 16) & 1u);
  return (unsigned short)(r >> 16);
}

// ---------- cast fp32 -> bf16 (vectorized x4) ----------
__global__ __launch_bounds__(256) void cast_kernel(const float* __restrict__ s,
                                                   unsigned short* __restrict__ d, int n4){
  int i = blockIdx.x * 256 + threadIdx.x;
  if (i >= n4) return;
  const float4 v = ((const float4*)s)[i];
  ushort4 o; o.x = f2bf(v.x); o.y = f2bf(v.y); o.z = f2bf(v.z); o.w = f2bf(v.w);
  ((ushort4*)d)[i] = o;
}

// ---------- concat 3 bias vectors of D_ each ----------
__global__ __launch_bounds__(256) void concat_bias(const float* __restrict__ a,
                                                   const float* __restrict__ b,
                                                   const float* __restrict__ c,
                                                   float* __restrict__ o){
  int i = blockIdx.x * 256 + threadIdx.x;
  if (i >= 3 * D_) return;
  o[i] = (i < D_) ? a[i] : (i < 2 * D_) ? b[i - D_] : c[i - 2 * D_];
}

// ---------- bf16 GEMM: C[M][N] = A[M][K] @ B[N][K]^T + bias[N]  (m97 recipe) ----------
typedef __attribute__((ext_vector_type(8))) short bfrag8;   // 8 bf16 = 4 VGPR
typedef __attribute__((ext_vector_type(4))) float facc4;    // 4 fp32 acc

__global__ __launch_bounds__(256, 2) void gemm_bt(
    const unsigned short* __restrict__ A,
    const unsigned short* __restrict__ Bw,
    const float* __restrict__ bias,
    unsigned short* __restrict__ C,
    int M, int N, int K)
{
  __shared__ __align__(16) unsigned short lA[128 * 32];
  __shared__ __align__(16) unsigned short lB[128 * 32];
  const int t = threadIdx.x;
  const int lane = t & 63, wid = t >> 6;
  const int wm = wid >> 1, wn = wid & 1;
  const size_t rowBase = (size_t)blockIdx.x * 128;
  const size_t colBase = (size_t)blockIdx.y * 128;
  const int sr = lane >> 2, sg = lane & 3;     // staging: 4 lanes/row, 16B each

  const unsigned short* gA0 = A  + (rowBase + (size_t)(wid * 16 + sr)) * K + sg * 8;
  const unsigned short* gB0 = Bw + (colBase + (size_t)(wid * 16 + sr)) * K + sg * 8;
  unsigned short* lA0 = &lA[(wid * 16) * 32];  // wave-uniform LDS base
  unsigned short* lB0 = &lB[(wid * 16) * 32];

  facc4 acc[4][4];
  #pragma unroll
  for (int i = 0; i < 4; i++)
    #pragma unroll
    for (int j = 0; j < 4; j++) acc[i][j] = 0;

  const int fm = lane & 15, quad = lane >> 4;
  const unsigned short* aAddr = &lA[(wm * 64 + fm) * 32 + quad * 8];
  const unsigned short* bAddr = &lB[(wn * 64 + fm) * 32 + quad * 8];

#define STAGE(k0) do { \
    __builtin_amdgcn_global_load_lds((const __attribute__((address_space(1))) void*)(gA0 + (k0)),                 (__attribute__((address_space(3))) void*)(lA0),            16, 0, 0); \
    __builtin_amdgcn_global_load_lds((const __attribute__((address_space(1))) void*)(gA0 + (size_t)64*K + (k0)),  (__attribute__((address_space(3))) void*)(lA0 + 64*32),    16, 0, 0); \
    __builtin_amdgcn_global_load_lds((const __attribute__((address_space(1))) void*)(gB0 + (k0)),                 (__attribute__((address_space(3))) void*)(lB0),            16, 0, 0); \
    __builtin_amdgcn_global_load_lds((const __attribute__((address_space(1))) void*)(gB0 + (size_t)64*K + (k0)),  (__attribute__((address_space(3))) void*)(lB0 + 64*32),    16, 0, 0); \
  } while (0)

  STAGE(0);
  __syncthreads();
  for (int kt = 0;;) {
    bfrag8 af[4], bf[4];
    #pragma unroll
    for (int i = 0; i < 4; i++) {
      af[i] = *(const bfrag8*)(aAddr + i * 16 * 32);
      bf[i] = *(const bfrag8*)(bAddr + i * 16 * 32);
    }
    #pragma unroll
    for (int i = 0; i < 4; i++)
      #pragma unroll
      for (int j = 0; j < 4; j++)
        acc[i][j] = __builtin_amdgcn_mfma_f32_16x16x32_bf16(af[i], bf[j], acc[i][j], 0, 0, 0);
    kt += 32;
    if (kt >= K) break;
    __syncthreads();
    STAGE(kt);
    __syncthreads();
  }
#undef STAGE

  // epilogue: D row = quad*4+rr, col = lane&15 (m89/m91-verified layout)
  #pragma unroll
  for (int i = 0; i < 4; i++) {
    const size_t r0 = rowBase + wm * 64 + i * 16 + quad * 4;
    #pragma unroll
    for (int j = 0; j < 4; j++) {
      const size_t cc = colBase + wn * 64 + j * 16 + fm;
      const float bv = bias[cc];
      #pragma unroll
      for (int rr = 0; rr < 4; rr++)
        C[(r0 + rr) * (size_t)N + cc] = f2bf(acc[i][j][rr] + bv);
    }
  }
}

// ---------- MFMA scores with K-split: Spart[b][ks][64][64] = q_chunk @ k_chunk^T ----------
// q rows at qkv + b*rowsPerBatch*QKVLD, k at column offset +2048. 64 rows processed
// (for SA2 rowsPerBatch=57: rows 57..63 are neighbor-batch garbage, ignored downstream).
__global__ __launch_bounds__(256) void scores_kernel(
    const unsigned short* __restrict__ qkv, int rowsPerBatch, float* __restrict__ Spart)
{
  __shared__ __align__(16) unsigned short lq[64 * 32];
  __shared__ __align__(16) unsigned short lk[64 * 32];
  const int b = blockIdx.x, ks = blockIdx.y;
  const int t = threadIdx.x, lane = t & 63, wid = t >> 6;
  const int sr = lane >> 2, sg = lane & 3;
  const unsigned short* gq = qkv + ((size_t)b * rowsPerBatch + wid * 16 + sr) * QKVLD
                             + ks * 256 + sg * 8;
  const unsigned short* gk = gq + 2048;
  unsigned short* lq0 = &lq[(wid * 16) * 32];
  unsigned short* lk0 = &lk[(wid * 16) * 32];
  const int fm = lane & 15, quad = lane >> 4;
  const unsigned short* aAddr = &lq[(wid * 16 + fm) * 32 + quad * 8];

  facc4 acc[4];
  #pragma unroll
  for (int j = 0; j < 4; j++) acc[j] = 0;

#define STAGE2(k0) do { \
    __builtin_amdgcn_global_load_lds((const __attribute__((address_space(1))) void*)(gq + (k0)), (__attribute__((address_space(3))) void*)(lq0), 16, 0, 0); \
    __builtin_amdgcn_global_load_lds((const __attribute__((address_space(1))) void*)(gk + (k0)), (__attribute__((address_space(3))) void*)(lk0), 16, 0, 0); \
  } while (0)

  STAGE2(0);
  __syncthreads();
  for (int kk = 0;;) {
    const bfrag8 af = *(const bfrag8*)aAddr;
    #pragma unroll
    for (int j = 0; j < 4; j++) {
      const bfrag8 bf = *(const bfrag8*)(&lk[(j * 16 + fm) * 32 + quad * 8]);
      acc[j] = __builtin_amdgcn_mfma_f32_16x16x32_bf16(af, bf, acc[j], 0, 0, 0);
    }
    kk += 32;
    if (kk >= 256) break;
    __syncthreads();
    STAGE2(kk);
    __syncthreads();
  }
#undef STAGE2

  float* sp = Spart + (size_t)(b * 8 + ks) * 4096;
  const int r0 = wid * 16 + quad * 4;
  #pragma unroll
  for (int j = 0; j < 4; j++)
    #pragma unroll
    for (int rr = 0; rr < 4; rr++)
      sp[(r0 + rr) * 64 + j * 16 + fm] = acc[j][rr];
}

// ---------- NSA finisher: reduce partials + band softmax column-sums ----------
__global__ __launch_bounds__(512) void nsa_fin(const float* __restrict__ Spart,
                                               float* __restrict__ cbuf){
  __shared__ float Ss[64][65];
  const int b = blockIdx.x, t = threadIdx.x;
  const float* sp = Spart + (size_t)b * 8 * 4096;
  for (int idx = t; idx < 4096; idx += 512) {
    float s = 0.f;
    #pragma unroll
    for (int ks = 0; ks < 8; ks++) s += sp[ks * 4096 + idx];
    Ss[idx >> 6][idx & 63] = s * SCALE_;
  }
  __syncthreads();
  if (t < W_ * 8) {
    const int wi = t >> 3, jp = t & 7;
    float csum = 0.f;
    for (int ip = 0; ip < 8; ip++) {
      const float* row = &Ss[wi + ip][wi];
      float mx = row[0];
      #pragma unroll
      for (int q = 1; q < 8; q++) mx = fmaxf(mx, row[q]);
      float s = 0.f, ej = 0.f;
      #pragma unroll
      for (int q = 0; q < 8; q++) { float e = __expf(row[q] - mx); s += e; if (q == jp) ej = e; }
      csum += ej / s;
    }
    cbuf[((size_t)b * W_ + wi) * 8 + jp] = csum;
  }
}

// ---------- SA2 finisher: reduce partials + softmax column-sums c2[b][j] ----------
__global__ __launch_bounds__(512) void sa2_c2(const float* __restrict__ Spart,
                                              float* __restrict__ c2buf){
  __shared__ float Ss[64][65];
  __shared__ float rowm[64], rowsum[64];
  const int b = blockIdx.x, t = threadIdx.x;
  const float* sp = Spart + (size_t)b * 8 * 4096;
  for (int idx = t; idx < 4096; idx += 512) {
    float s = 0.f;
    #pragma unroll
    for (int ks = 0; ks < 8; ks++) s += sp[ks * 4096 + idx];
    Ss[idx >> 6][idx & 63] = s * SCALE_;
  }
  __syncthreads();
  if (t < W_) {
    float mx = -1e30f;
    for (int j = 0; j < W_; j++) mx = fmaxf(mx, Ss[t][j]);
    float s = 0.f;
    for (int j = 0; j < W_; j++) s += __expf(Ss[t][j] - mx);
    rowm[t] = mx; rowsum[t] = 1.f / s;
  }
  __syncthreads();
  if (t < W_) {
    float cs = 0.f;
    for (int i = 0; i < W_; i++) cs += __expf(Ss[i][t] - rowm[i]) * rowsum[i];
    c2buf[(size_t)b * 64 + t] = cs;
  }
}

// ---------- output combine: out[b][d] = sum_j c2[b][j] * v2[b*57+j][d] ----------
__global__ __launch_bounds__(256) void outcomb(const unsigned short* __restrict__ qkv2,
                                               const float* __restrict__ c2buf,
                                               float* __restrict__ out){
  const int b = blockIdx.y;
  const int d = blockIdx.x * 256 + threadIdx.x;
  __shared__ float c2[W_];
  if (threadIdx.x < W_) c2[threadIdx.x] = c2buf[(size_t)b * 64 + threadIdx.x];
  __syncthreads();
  const unsigned short* v = qkv2 + (size_t)b * W_ * QKVLD + 4096 + d;
  float a = 0.f;
  for (int j = 0; j < W_; j++) a += c2[j] * bf2f(v[(size_t)j * QKVLD]);
  out[(size_t)b * 2048 + d] = a;
}

// ---------- h = fc @ ds_w^T (per-batch) + ds_b + nsa combine ----------
__global__ __launch_bounds__(256) void h_kernel(
    const float* __restrict__ fc, const float* __restrict__ dsw,
    const float* __restrict__ dsb, const unsigned short* __restrict__ qkv,
    const float* __restrict__ cbuf, float* __restrict__ h)
{
  const int b = blockIdx.y;
  const int d = blockIdx.x * 256 + threadIdx.x;
  __shared__ __align__(16) float dswl[W_ * 64];
  __shared__ float dsbl[W_];
  __shared__ float cl[W_ * 8];
  for (int i = threadIdx.x; i < W_ * 64; i += 256) dswl[i] = dsw[i];
  for (int i = threadIdx.x; i < W_ * 8; i += 256) cl[i] = cbuf[(size_t)b * W_ * 8 + i];
  if (threadIdx.x < W_) dsbl[threadIdx.x] = dsb[threadIdx.x];
  __syncthreads();
  float f[64];
  #pragma unroll
  for (int n = 0; n < 64; n++) f[n] = fc[((size_t)b * 64 + n) * 2048 + d];
  const unsigned short* vcol = qkv + (size_t)b * 64 * QKVLD + 4096 + d;
  float* hcol = h + (size_t)b * W_ * 2048 + d;
  for (int w = 0; w < W_; w++) {
    float acc = dsbl[w];
    const float4* dw4 = (const float4*)&dswl[w * 64];
    #pragma unroll
    for (int n4 = 0; n4 < 16; n4++) {
      const float4 dv = dw4[n4];
      acc += f[4*n4+0]*dv.x + f[4*n4+1]*dv.y + f[4*n4+2]*dv.z + f[4*n4+3]*dv.w;
    }
    float an = 0.f;
    #pragma unroll
    for (int j = 0; j < 8; j++) an += cl[w * 8 + j] * bf2f(vcol[(size_t)(w + j) * QKVLD]);
    hcol[(size_t)w * 2048] = acc + an;
  }
}

// ---------- LayerNorm + cast to bf16 (pads rows [3648,3712) with zeros) ----------
__global__ __launch_bounds__(256) void ln_kernel(
    const float* __restrict__ h, const float* __restrict__ g,
    const float* __restrict__ be, unsigned short* __restrict__ hn)
{
  const int r = blockIdx.x, t = threadIdx.x;
  unsigned short* orow = hn + (size_t)r * 2048;
  if (r >= B_ * W_) {
    for (int i = t; i < 2048; i += 256) orow[i] = 0;
    return;
  }
  const float* row = h + (size_t)r * 2048;
  const float4 v0 = ((const float4*)row)[t];
  const float4 v1 = ((const float4*)row)[t + 256];
  float s  = v0.x + v0.y + v0.z + v0.w + v1.x + v1.y + v1.z + v1.w;
  float s2 = v0.x*v0.x + v0.y*v0.y + v0.z*v0.z + v0.w*v0.w
           + v1.x*v1.x + v1.y*v1.y + v1.z*v1.z + v1.w*v1.w;
  #pragma unroll
  for (int off = 32; off >= 1; off >>= 1) { s += __shfl_down(s, off); s2 += __shfl_down(s2, off); }
  __shared__ float rs[4], rs2[4];
  if ((t & 63) == 0) { rs[t >> 6] = s; rs2[t >> 6] = s2; }
  __syncthreads();
  const float st  = rs[0] + rs[1] + rs[2] + rs[3];
  const float s2t = rs2[0] + rs2[1] + rs2[2] + rs2[3];
  const float mu  = st * (1.f / 2048.f);
  const float var = s2t * (1.f / 2048.f) - mu * mu;
  const float rstd = rsqrtf(var + 1e-5f);
  const float4 g0 = ((const float4*)g)[t],  g1 = ((const float4*)g)[t + 256];
  const float4 b0 = ((const float4*)be)[t], b1 = ((const float4*)be)[t + 256];
  ushort4 o0, o1;
  o0.x = f2bf((v0.x - mu) * rstd * g0.x + b0.x);
  o0.y = f2bf((v0.y - mu) * rstd * g0.y + b0.y);
  o0.z = f2bf((v0.z - mu) * rstd * g0.z + b0.z);
  o0.w = f2bf((v0.w - mu) * rstd * g0.w + b0.w);
  o1.x = f2bf((v1.x - mu) * rstd * g1.x + b1.x);
  o1.y = f2bf((v1.y - mu) * rstd * g1.y + b1.y);
  o1.z = f2bf((v1.z - mu) * rstd * g1.z + b1.z);
  o1.w = f2bf((v1.w - mu) * rstd * g1.w + b1.w);
  ((ushort4*)orow)[t] = o0;
  ((ushort4*)orow)[t + 256] = o1;
}

// ---------- launch ----------
extern "C" void kernel_launch(void* const* d_in, const int* in_sizes, int n_in,
                              void* d_out, int out_size, void* d_ws, size_t ws_size,
                              hipStream_t stream)
{
  const float* fc  = (const float*)d_in[0];
  const float* nwq = (const float*)d_in[1];
  const float* nbq = (const float*)d_in[2];
  const float* nwk = (const float*)d_in[3];
  const float* nbk = (const float*)d_in[4];
  const float* nwv = (const float*)d_in[5];
  const float* nbv = (const float*)d_in[6];
  const float* dsw = (const float*)d_in[7];
  const float* dsb = (const float*)d_in[8];
  const float* lng = (const float*)d_in[9];
  const float* lnb = (const float*)d_in[10];
  const float* swq = (const float*)d_in[11];
  const float* sbq = (const float*)d_in[12];
  const float* swk = (const float*)d_in[13];
  const float* sbk = (const float*)d_in[14];
  const float* swv = (const float*)d_in[15];
  const float* sbv = (const float*)d_in[16];

  char* ws = (char*)d_ws;
  unsigned short* fc16 = (unsigned short*)(ws + 0);          // 16,777,216 B
  unsigned short* wcat = (unsigned short*)(ws + 16777216);   // 25,165,824 B (reused: Spart)
  float* Spart         = (float*)(ws + 16777216);            // 8,388,608 B — aliases wcat (disjoint lifetime)
  float* bcat1         = (float*)(ws + 41943040);            // 24,576 B
  float* bcat2         = (float*)(ws + 41967616);            // 24,576 B
  unsigned short* qkv  = (unsigned short*)(ws + 41992192);   // 50,331,648 B (reused for q2k2v2)
  float* cbuf          = (float*)(ws + 92323840);            // 116,736 B (reused: c2buf)
  float* c2buf         = (float*)(ws + 92323840);            // aliases cbuf (disjoint lifetime)
  float* hbuf          = (float*)(ws + 92440576);            // 29,884,416 B
  unsigned short* hn   = (unsigned short*)(ws + 122324992);  // 15,204,352 B  (total ~137.5 MB)

  // casts + bias concat (nsa)
  cast_kernel<<<8192, 256, 0, stream>>>(fc, fc16, 2097152);
  cast_kernel<<<4096, 256, 0, stream>>>(nwq, wcat,            1048576);
  cast_kernel<<<4096, 256, 0, stream>>>(nwk, wcat + 4194304,  1048576);
  cast_kernel<<<4096, 256, 0, stream>>>(nwv, wcat + 8388608,  1048576);
  concat_bias<<<24, 256, 0, stream>>>(nbq, nbk, nbv, bcat1);

  // qkv = fc16 @ [wq;wk;wv]^T + bias   (M=4096, N=6144, K=2048)
  gemm_bt<<<dim3(32, 48), 256, 0, stream>>>(fc16, wcat, bcat1, qkv, 4096, 6144, 2048);

  // NSA band scores via MFMA, K-split x8 (Spart overwrites wcat — gemm1 done)
  scores_kernel<<<dim3(64, 8), 256, 0, stream>>>(qkv, 64, Spart);
  nsa_fin<<<64, 512, 0, stream>>>(Spart, cbuf);

  // h = ds-projection + nsa combine
  h_kernel<<<dim3(8, 64), 256, 0, stream>>>(fc, dsw, dsb, qkv, cbuf, hbuf);

  // LayerNorm -> hn (bf16, padded to 3712 rows)
  ln_kernel<<<3712, 256, 0, stream>>>(hbuf, lng, lnb, hn);

  // casts + bias concat (sa) — Spart dead, wcat region reused for sa weights
  cast_kernel<<<4096, 256, 0, stream>>>(swq, wcat,            1048576);
  cast_kernel<<<4096, 256, 0, stream>>>(swk, wcat + 4194304,  1048576);
  cast_kernel<<<4096, 256, 0, stream>>>(swv, wcat + 8388608,  1048576);
  concat_bias<<<24, 256, 0, stream>>>(sbq, sbk, sbv, bcat2);

  // q2k2v2 = hn @ [wq;wk;wv]^T + bias  (M=3712 padded, N=6144, K=2048)
  gemm_bt<<<dim3(29, 48), 256, 0, stream>>>(hn, wcat, bcat2, qkv, 3712, 6144, 2048);

  // SA2 scores via MFMA (Spart overwrites sa weights — gemm2 done).
  // Rows b*57..b*57+63: max row read 63*57+63 = 3654 < 3712, in-bounds.
  scores_kernel<<<dim3(64, 8), 256, 0, stream>>>(qkv, W_, Spart);
  sa2_c2<<<64, 512, 0, stream>>>(Spart, c2buf);

  // final output combine -> out (B, D) fp32
  outcomb<<<dim3(8, 64), 256, 0, stream>>>(qkv, c2buf, (float*)d_out);

  (void)in_sizes; (void)n_in; (void)out_size; (void)ws_size;
}